// Round 6
// baseline (1345.763 us; speedup 1.0000x reference)
//
#include <hip/hip_runtime.h>

#define DIM 128
#define K_CL 512
#define BM 128          // points per block tile
#define CC 128          // centers per chunk (4 chunks)
#define GAPU 4352u      // tier-1 routing gap in d'-ulps (2^-12): ~0.81 + pack noise
#define TAU2 0.02f      // hi/lo-split margin -> tier-3 (fp64 rescue)
#define LISTA_CAP 65536
#define LISTB_CAP 16384

typedef unsigned int uint;
typedef unsigned short ushort;
using short8 = __attribute__((ext_vector_type(8))) short;
using f32x4  = __attribute__((ext_vector_type(4))) float;
using us8    = __attribute__((ext_vector_type(8))) unsigned short;

__device__ __forceinline__ ushort f2bf(float x) {
    uint u = __float_as_uint(x);
    u += 0x7fff + ((u >> 16) & 1);          // RNE
    return (ushort)(u >> 16);
}
__device__ __forceinline__ float bf2f(ushort h) {
    return __uint_as_float(((uint)h) << 16);
}
__device__ __forceinline__ uint umn(uint a, uint b) { return a < b ? a : b; }
__device__ __forceinline__ uint umx(uint a, uint b) { return a > b ? a : b; }

__device__ __forceinline__ void gload_lds16(const void* gsrc, void* ldst) {
    __builtin_amdgcn_global_load_lds(
        (const __attribute__((address_space(1))) unsigned int*)gsrc,
        (__attribute__((address_space(3))) unsigned int*)ldst,
        16, 0, 0);
}

// ---------------- kernel A: c2 (raw), c2q (offset for tier1), c2d (fp64) ----------------
__global__ void c2_kernel(const float* __restrict__ C, float* __restrict__ c2,
                          float* __restrict__ c2q, double* __restrict__ c2d) {
    int k = blockIdx.x * 256 + threadIdx.x;
    if (k < K_CL) {
        const float* row = C + (size_t)k * DIM;
        float s = 0.f;
        double sd = 0.0;
        for (int d = 0; d < DIM; ++d) {
            s = fmaf(row[d], row[d], s);
            double v = (double)row[d];
            sd += v * v;
        }
        c2[k] = s;
        c2q[k] = s + 3072.0f;   // d' = c2q - 2*dot  in [2048,4096)
        c2d[k] = sd;
    }
}

// ---------------- kernel A2: split C into bf16 hi|lo ----------------
__global__ void convC_kernel(const float* __restrict__ C, ushort* __restrict__ Cp) {
    int e = blockIdx.x * 256 + threadIdx.x;   // 0..65535
    if (e < K_CL * DIM) {
        int p = e >> 7, d = e & 127;
        float x = C[e];
        ushort h = f2bf(x);
        float lo = x - bf2f(h);
        Cp[(size_t)p * 256 + d] = h;
        Cp[(size_t)p * 256 + 128 + d] = f2bf(lo);
    }
}

// ---------------- TIER 1: hi-only MFMA GEMM + packed-u32 argmin ----------------
__global__ __launch_bounds__(256, 2)
void assign_hi(const float* __restrict__ F, const ushort* __restrict__ Cp,
               const float* __restrict__ c2qg, float* __restrict__ assign_out,
               int* __restrict__ cntA, int* __restrict__ listA,
               int* __restrict__ cntB, int* __restrict__ listB, int N) {
    __shared__ __align__(16) ushort Fs[BM * 128];    // 32768 B
    __shared__ __align__(16) ushort Cs[128 * 128];   // 32768 B

    const int tid  = threadIdx.x;
    const int lane = tid & 63;
    const int wave = tid >> 6;
    const int quad = lane >> 4;
    const int l15  = lane & 15;
    const int wy   = wave >> 1;     // point half
    const int wx   = wave & 1;      // center half
    const int p0   = blockIdx.x * BM;

    // ---- stage Fs: fp32 -> bf16 hi, swizzled ----
#pragma unroll
    for (int t = 0; t < 8; ++t) {
        int G = tid + 256 * t;          // 0..2047 granules
        int r = G >> 4, pos = G & 15;
        int g = (pos & 8) | ((pos ^ r) & 7);
        int gp = p0 + r; if (gp >= N) gp = N - 1;
        const float* src = F + (size_t)gp * DIM + g * 8;
        float4 x0 = ((const float4*)src)[0];
        float4 x1 = ((const float4*)src)[1];
        us8 o;
        o[0] = f2bf(x0.x); o[1] = f2bf(x0.y); o[2] = f2bf(x0.z); o[3] = f2bf(x0.w);
        o[4] = f2bf(x1.x); o[5] = f2bf(x1.y); o[6] = f2bf(x1.z); o[7] = f2bf(x1.w);
        *((us8*)&Fs[(size_t)G * 8]) = o;
    }

    // ---- precompute offsets ----
    int prA[4], xA[4], cnB[4], xB[4];
#pragma unroll
    for (int i = 0; i < 4; ++i) {
        int pr = wy * 64 + i * 16 + l15;
        prA[i] = pr * 128; xA[i] = quad ^ (pr & 7);
    }
#pragma unroll
    for (int j = 0; j < 4; ++j) {
        int cn = wx * 64 + j * 16 + l15;
        cnB[j] = cn * 128; xB[j] = quad ^ (cn & 7);
    }
    int csrc[8];
#pragma unroll
    for (int t = 0; t < 8; ++t) {
        int G = t * 256 + wave * 64 + lane;
        int r = G >> 4, pos = G & 15;
        int g = (pos & 8) | ((pos ^ r) & 7);
        csrc[t] = r * 256 + g * 8;      // elem offset within chunk (hi half)
    }
    float c2q[4][4];
    uint  kb [4][4];
#pragma unroll
    for (int cc = 0; cc < 4; ++cc)
#pragma unroll
        for (int j = 0; j < 4; ++j) {
            int k = cc * CC + wx * 64 + j * 16 + l15;
            c2q[cc][j] = c2qg[k];
            kb [cc][j] = (uint)k;
        }

    uint m1[16], m2[16];
#pragma unroll
    for (int i = 0; i < 16; ++i) { m1[i] = 0xFFFFFFFFu; m2[i] = 0xFFFFFFFFu; }

#pragma unroll 1
    for (int cc = 0; cc < 4; ++cc) {
        f32x4 acc[4][4];
#pragma unroll
        for (int i = 0; i < 4; ++i)
#pragma unroll
            for (int j = 0; j < 4; ++j) acc[i][j] = f32x4{0.f, 0.f, 0.f, 0.f};

        __syncthreads();   // Cs free (also covers Fs writes on cc=0)
#pragma unroll
        for (int t = 0; t < 8; ++t)
            gload_lds16(Cp + (size_t)cc * CC * 256 + csrc[t],
                        &Cs[(size_t)(t * 256 + wave * 64) * 8]);
        __syncthreads();   // staging complete

#pragma unroll
        for (int s = 0; s < 4; ++s) {
            const int hs = (s & 2) << 2;
            const int ls = (s & 1) << 2;
            short8 a[4], b[4];
#pragma unroll
            for (int j = 0; j < 4; ++j)
                b[j] = *((const short8*)&Cs[cnB[j] + (hs | (xB[j] ^ ls)) * 8]);
#pragma unroll
            for (int i = 0; i < 4; ++i)
                a[i] = *((const short8*)&Fs[prA[i] + (hs | (xA[i] ^ ls)) * 8]);
#pragma unroll
            for (int i = 0; i < 4; ++i)
#pragma unroll
                for (int j = 0; j < 4; ++j)
                    acc[i][j] = __builtin_amdgcn_mfma_f32_16x16x32_bf16(
                        a[i], b[j], acc[i][j], 0, 0, 0);
        }

        // ---- epilogue: packed (dist|k) dual-min, 5 VALU/value ----
#pragma unroll
        for (int i = 0; i < 4; ++i)
#pragma unroll
            for (int reg = 0; reg < 4; ++reg) {
                int lr = i * 4 + reg;
#pragma unroll
                for (int j = 0; j < 4; ++j) {
                    float dq = fmaf(acc[i][j][reg], -2.0f, c2q[cc][j]);
                    uint x = (__float_as_uint(dq) & 0xFFFFFE00u) | kb[cc][j];
                    uint t = umx(x, m1[lr]);
                    m2[lr] = umn(m2[lr], t);
                    m1[lr] = umn(m1[lr], x);
                }
            }
    }

    // ---- reduce across the 16 l15 lanes (dual-min merge) ----
#pragma unroll
    for (int lr = 0; lr < 16; ++lr) {
        uint a1 = m1[lr], a2 = m2[lr];
#pragma unroll
        for (int m = 1; m <= 8; m <<= 1) {
            uint o1 = (uint)__shfl_xor((int)a1, m);
            uint o2 = (uint)__shfl_xor((int)a2, m);
            uint hi = umx(a1, o1);
            a1 = umn(a1, o1);
            a2 = umn(umn(a2, o2), hi);
        }
        m1[lr] = a1; m2[lr] = a2;
    }

    __syncthreads();            // done with Cs; reuse as merge scratch
    uint* sm1 = (uint*)Cs;      // [2][128]
    uint* sm2 = sm1 + 256;

    if (l15 == 0) {
#pragma unroll
        for (int lr = 0; lr < 16; ++lr) {
            int pl = wy * 64 + (lr >> 2) * 16 + quad * 4 + (lr & 3);
            sm1[wx * 128 + pl] = m1[lr];
            sm2[wx * 128 + pl] = m2[lr];
        }
    }
    __syncthreads();

    if (tid < BM) {
        int p = p0 + tid;
        if (p < N) {
            uint a1 = sm1[tid], a2 = sm2[tid];
            uint b1 = sm1[128 + tid], b2 = sm2[128 + tid];
            uint hi = umx(a1, b1);
            uint M1 = umn(a1, b1);
            uint M2 = umn(umn(a2, b2), hi);
            assign_out[p] = (float)(M1 & 511u);
            if ((M2 & 0xFFFFFE00u) - (M1 & 0xFFFFFE00u) < GAPU) {
                int idx = atomicAdd(cntA, 1);
                if (idx < LISTA_CAP) listA[idx] = p;
                else {   // overflow valve -> fp64 tier
                    int ib = atomicAdd(cntB, 1);
                    if (ib < LISTB_CAP) listB[ib] = p;
                }
            }
        }
    }
}

// ---------------- TIER 2: hi/lo-split MFMA re-rank of listA points ----------------
__global__ __launch_bounds__(256, 2)
void assign_lohi(const float* __restrict__ F, const ushort* __restrict__ Cp,
                 const float* __restrict__ c2g, float* __restrict__ assign_out,
                 const int* __restrict__ cntA, const int* __restrict__ listA,
                 int* __restrict__ cntB, int* __restrict__ listB, int N) {
    int cnt = *cntA; if (cnt > LISTA_CAP) cnt = LISTA_CAP;
    const int p0 = blockIdx.x * BM;
    if (p0 >= cnt) return;

    __shared__ __align__(16) ushort Fs[BM * 256];   // 65536 B
    __shared__ __align__(16) ushort Cs[CC * 64];    // 16384 B

    const int tid  = threadIdx.x;
    const int lane = tid & 63;
    const int wave = tid >> 6;
    const int quad = lane >> 4;
    const int l15  = lane & 15;
    const int wy   = wave >> 1;
    const int wx   = wave & 1;

    for (int G = tid; G < BM * 32; G += 256) {
        int r = G >> 5, pos = G & 31;
        int g = (pos & 24) | ((pos ^ r) & 7);
        int idx = p0 + r; if (idx >= cnt) idx = cnt - 1;
        int gp = listA[idx];
        const float* src = F + (size_t)gp * DIM + (g & 15) * 8;
        float4 x0 = ((const float4*)src)[0];
        float4 x1 = ((const float4*)src)[1];
        float xs[8] = {x0.x, x0.y, x0.z, x0.w, x1.x, x1.y, x1.z, x1.w};
        us8 o;
        if (g < 16) {
#pragma unroll
            for (int t = 0; t < 8; ++t) o[t] = f2bf(xs[t]);
        } else {
#pragma unroll
            for (int t = 0; t < 8; ++t) {
                ushort h = f2bf(xs[t]);
                o[t] = f2bf(xs[t] - bf2f(h));
            }
        }
        *((us8*)&Fs[(size_t)G * 8]) = o;
    }

    int aoff[4][2], boff[4][2];
#pragma unroll
    for (int i = 0; i < 4; ++i) {
        int pr = wy * 64 + i * 16 + l15;
#pragma unroll
        for (int s = 0; s < 2; ++s)
            aoff[i][s] = pr * 256 + (((s * 4 + quad) ^ (pr & 7)) * 8);
    }
#pragma unroll
    for (int j = 0; j < 4; ++j) {
        int cn = wx * 64 + j * 16 + l15;
#pragma unroll
        for (int s = 0; s < 2; ++s)
            boff[j][s] = cn * 64 + (((s * 4 + quad) ^ (cn & 7)) * 8);
    }
    int cpoff[4];
    ushort* ldsdst[4];
#pragma unroll
    for (int t = 0; t < 4; ++t) {
        int Gbase = t * 256 + wave * 64;
        int G = Gbase + lane;
        int r = G >> 3, pos = G & 7;
        int g = pos ^ (r & 7);
        cpoff[t] = r * 256 + g * 8;
        ldsdst[t] = &Cs[(size_t)Gbase * 8];
    }

    float best1[16], best2[16];
    int bidx[16];
#pragma unroll
    for (int i = 0; i < 16; ++i) { best1[i] = 3.4e38f; best2[i] = 3.4e38f; bidx[i] = 0; }

    for (int cc = 0; cc < K_CL / CC; ++cc) {
        const int ccbase = cc * (CC * 256);
        f32x4 acc[4][4];
#pragma unroll
        for (int i = 0; i < 4; ++i)
#pragma unroll
            for (int j = 0; j < 4; ++j) acc[i][j] = f32x4{0.f, 0.f, 0.f, 0.f};

#pragma unroll
        for (int st = 0; st < 4; ++st) {
            const int ak0 = st & 1;
            const int ak1 = (st < 2) ? (st + 2) : -1;

            __syncthreads();
#pragma unroll
            for (int t = 0; t < 4; ++t)
                gload_lds16(Cp + ccbase + st * 64 + cpoff[t], ldsdst[t]);
            __syncthreads();

#pragma unroll
            for (int s = 0; s < 2; ++s) {
                short8 b[4], a[4];
#pragma unroll
                for (int j = 0; j < 4; ++j)
                    b[j] = *((const short8*)&Cs[boff[j][s]]);
#pragma unroll
                for (int i = 0; i < 4; ++i)
                    a[i] = *((const short8*)&Fs[aoff[i][s] + ak0 * 64]);
#pragma unroll
                for (int i = 0; i < 4; ++i)
#pragma unroll
                    for (int j = 0; j < 4; ++j)
                        acc[i][j] = __builtin_amdgcn_mfma_f32_16x16x32_bf16(
                            a[i], b[j], acc[i][j], 0, 0, 0);
                if (ak1 >= 0) {
#pragma unroll
                    for (int i = 0; i < 4; ++i)
                        a[i] = *((const short8*)&Fs[aoff[i][s] + ak1 * 64]);
#pragma unroll
                    for (int i = 0; i < 4; ++i)
#pragma unroll
                        for (int j = 0; j < 4; ++j)
                            acc[i][j] = __builtin_amdgcn_mfma_f32_16x16x32_bf16(
                                a[i], b[j], acc[i][j], 0, 0, 0);
                }
            }
        }

        float c2v[4];
#pragma unroll
        for (int j = 0; j < 4; ++j)
            c2v[j] = c2g[cc * CC + wx * 64 + j * 16 + l15];
#pragma unroll
        for (int i = 0; i < 4; ++i)
#pragma unroll
            for (int reg = 0; reg < 4; ++reg) {
                int lr = i * 4 + reg;
#pragma unroll
                for (int j = 0; j < 4; ++j) {
                    float d = c2v[j] - 2.0f * acc[i][j][reg];
                    int k = cc * CC + wx * 64 + j * 16 + l15;
                    if (d < best1[lr]) { best2[lr] = best1[lr]; best1[lr] = d; bidx[lr] = k; }
                    else if (d < best2[lr]) best2[lr] = d;
                }
            }
    }

    __syncthreads();
    float* sb1 = (float*)Cs;
    float* sb2 = sb1 + 256;
    int*   sk  = (int*)(sb2 + 256);

#pragma unroll
    for (int lr = 0; lr < 16; ++lr) {
        float b1 = best1[lr], b2 = best2[lr];
        int k1 = bidx[lr];
#pragma unroll
        for (int m = 1; m <= 8; m <<= 1) {
            float ob1 = __shfl_xor(b1, m);
            float ob2 = __shfl_xor(b2, m);
            int   ok1 = __shfl_xor(k1, m);
            float nb2 = fminf(fmaxf(b1, ob1), fminf(b2, ob2));
            if (ob1 < b1 || (ob1 == b1 && ok1 < k1)) { b1 = ob1; k1 = ok1; }
            b2 = nb2;
        }
        best1[lr] = b1; best2[lr] = b2; bidx[lr] = k1;
    }
    if (l15 == 0) {
#pragma unroll
        for (int lr = 0; lr < 16; ++lr) {
            int pl = wy * 64 + (lr >> 2) * 16 + quad * 4 + (lr & 3);
            sb1[wx * 128 + pl] = best1[lr];
            sb2[wx * 128 + pl] = best2[lr];
            sk [wx * 128 + pl] = bidx[lr];
        }
    }
    __syncthreads();

    if (tid < BM && p0 + tid < cnt) {
        int p = listA[p0 + tid];
        float a1 = sb1[tid],       a2 = sb2[tid];        int akk = sk[tid];
        float c1 = sb1[128 + tid], cs2 = sb2[128 + tid]; int ckk = sk[128 + tid];
        float m2v = fminf(fmaxf(a1, c1), fminf(a2, cs2));
        float m1v; int mk;
        if (c1 < a1 || (c1 == a1 && ckk < akk)) { m1v = c1; mk = ckk; }
        else                                    { m1v = a1; mk = akk; }
        assign_out[p] = (float)mk;
        if (m2v - m1v < TAU2) {
            int ib = atomicAdd(cntB, 1);
            if (ib < LISTB_CAP) listB[ib] = p;
        }
    }
}

// ---------------- TIER 3: fp64 re-argmin for near-tie points ----------------
__global__ void rescue_kernel(const float* __restrict__ F, const float* __restrict__ C,
                              const double* __restrict__ c2d,
                              const int* __restrict__ cntB,
                              const int* __restrict__ listB,
                              float* __restrict__ assign_out) {
    __shared__ double Frow[DIM];
    __shared__ double bd[256];
    __shared__ int    bk[256];
    int cnt = *cntB;
    if (cnt > LISTB_CAP) cnt = LISTB_CAP;
    for (int r = blockIdx.x; r < cnt; r += gridDim.x) {
        int p = listB[r];
        if (threadIdx.x < DIM) Frow[threadIdx.x] = (double)F[(size_t)p * DIM + threadIdx.x];
        __syncthreads();
        double b1 = 1e300; int k1 = 0x7fffffff;
        for (int k = threadIdx.x; k < K_CL; k += 256) {
            const float* c = C + (size_t)k * DIM;
            double acc = 0.0;
            for (int d = 0; d < DIM; ++d) acc += Frow[d] * (double)c[d];
            double dd = c2d[k] - 2.0 * acc;
            if (dd < b1 || (dd == b1 && k < k1)) { b1 = dd; k1 = k; }
        }
        bd[threadIdx.x] = b1; bk[threadIdx.x] = k1;
        __syncthreads();
        for (int s = 128; s > 0; s >>= 1) {
            if (threadIdx.x < s) {
                double ob = bd[threadIdx.x + s]; int ok = bk[threadIdx.x + s];
                if (ob < bd[threadIdx.x] || (ob == bd[threadIdx.x] && ok < bk[threadIdx.x])) {
                    bd[threadIdx.x] = ob; bk[threadIdx.x] = ok;
                }
            }
            __syncthreads();
        }
        if (threadIdx.x == 0) assign_out[p] = (float)bk[0];
        __syncthreads();
    }
}

// ---------------- S1: per-cluster counts ----------------
__global__ void count_kernel(const float* __restrict__ assign_f,
                             int* __restrict__ gcount, int N) {
    int p = blockIdx.x * 256 + threadIdx.x;
    if (p < N) atomicAdd(&gcount[(int)assign_f[p]], 1);
}

// ---------------- S2: exclusive scan + cursor init (1 block, 512 thr) ----------------
__global__ void scan_kernel(const int* __restrict__ gcount,
                            int* __restrict__ offsets, int* __restrict__ cursor, int N) {
    __shared__ int s[K_CL];
    int t = threadIdx.x;
    int v = gcount[t];
    s[t] = v;
    __syncthreads();
    for (int off = 1; off < K_CL; off <<= 1) {
        int x = (t >= off) ? s[t - off] : 0;
        __syncthreads();
        s[t] += x;
        __syncthreads();
    }
    offsets[t] = s[t] - v;
    cursor[t]  = s[t] - v;
    if (t == K_CL - 1) offsets[K_CL] = N;
}

// ---------------- S3: scatter point indices into cluster-contiguous order ----------------
__global__ void scatter_kernel(const float* __restrict__ assign_f,
                               int* __restrict__ cursor, int* __restrict__ idx, int N) {
    int p = blockIdx.x * 256 + threadIdx.x;
    if (p < N) {
        int a = (int)assign_f[p];
        int pos = atomicAdd(&cursor[a], 1);
        idx[pos] = p;
    }
}

// ---------------- S4: gather-mean, one block per cluster ----------------
__global__ __launch_bounds__(256)
void gather_kernel(const float* __restrict__ F, const int* __restrict__ idx,
                   const int* __restrict__ offsets, float* __restrict__ out) {
    __shared__ float comb[DIM];
    const int k   = blockIdx.x;
    const int tid = threadIdx.x;
    const int rg  = tid >> 6;        // 4 row-groups of 64 lanes
    const int d2  = tid & 63;        // float2 column
    const int off = offsets[k];
    const int end = offsets[k + 1];
    const int cnt = end - off;

    if (tid < DIM) comb[tid] = 0.f;
    __syncthreads();

    float ax = 0.f, ay = 0.f;
    const float2* F2 = (const float2*)F;
    for (int m0 = off + rg * 4; m0 < end; m0 += 16) {
        float2 v[4]; int have[4];
#pragma unroll
        for (int t = 0; t < 4; ++t) {
            int m = m0 + t;
            have[t] = (m < end);
            int p = have[t] ? idx[m] : 0;
            v[t] = F2[(size_t)p * 64 + d2];
        }
#pragma unroll
        for (int t = 0; t < 4; ++t)
            if (have[t]) { ax += v[t].x; ay += v[t].y; }
    }
    atomicAdd(&comb[d2 * 2],     ax);
    atomicAdd(&comb[d2 * 2 + 1], ay);
    __syncthreads();

    if (tid < DIM) {
        float scale = 1.0f / (float)(cnt > 0 ? cnt : 1);
        out[(size_t)k * DIM + tid] = comb[tid] * scale;
    }
}

extern "C" void kernel_launch(void* const* d_in, const int* in_sizes, int n_in,
                              void* d_out, int out_size, void* d_ws, size_t ws_size,
                              hipStream_t stream) {
    const float* F = (const float*)d_in[0];
    const float* C = (const float*)d_in[1];
    int N = in_sizes[0] / DIM;               // 200000

    float* out = (float*)d_out;
    float* centers_out = out;                // [512*128]
    float* assign_out  = out + K_CL * DIM;   // [N], as float

    // workspace layout (~1.2 MB)
    int*    cntA    = (int*)d_ws;                    // [0]=A, [1]=B (8 ints)
    int*    cntB    = cntA + 1;
    int*    gcount  = cntA + 8;                      // 512
    int*    cursor  = gcount + K_CL;                 // 512
    int*    offsets = cursor + K_CL;                 // 516 (513 used)
    int*    listA   = offsets + 516;                 // 65536
    int*    listB   = listA + LISTA_CAP;             // 16384
    float*  c2      = (float*)(listB + LISTB_CAP);   // 512
    float*  c2q     = c2 + K_CL;                     // 512
    double* c2d     = (double*)(c2q + K_CL);         // 512 (8B-aligned)
    ushort* Cp      = (ushort*)(c2d + K_CL);         // 512*256
    int*    idx     = (int*)(Cp + K_CL * 256);       // 200000

    // zero cntA/cntB + gcount
    hipMemsetAsync(d_ws, 0, (8 + K_CL) * sizeof(int), stream);

    c2_kernel<<<2, 256, 0, stream>>>(C, c2, c2q, c2d);
    convC_kernel<<<K_CL * DIM / 256, 256, 0, stream>>>(C, Cp);

    int nb = (N + BM - 1) / BM;              // 1563
    assign_hi<<<nb, 256, 0, stream>>>(F, Cp, c2q, assign_out, cntA, listA, cntB, listB, N);

    assign_lohi<<<LISTA_CAP / BM, 256, 0, stream>>>(F, Cp, c2, assign_out,
                                                    cntA, listA, cntB, listB, N);

    rescue_kernel<<<256, 256, 0, stream>>>(F, C, c2d, cntB, listB, assign_out);

    int pb = (N + 255) / 256;                // 782
    count_kernel  <<<pb, 256, 0, stream>>>(assign_out, gcount, N);
    scan_kernel   <<<1, K_CL, 0, stream>>>(gcount, offsets, cursor, N);
    scatter_kernel<<<pb, 256, 0, stream>>>(assign_out, cursor, idx, N);
    gather_kernel <<<K_CL, 256, 0, stream>>>(F, idx, offsets, centers_out);
}

// Round 7
// 336.824 us; speedup vs baseline: 3.9955x; 3.9955x over previous
//
#include <hip/hip_runtime.h>

#define DIM 128
#define K_CL 512
#define BM 128          // points per block tile
#define CC 128          // centers per chunk (4 chunks)
#define GAPU 4352u      // tier-1 routing gap in d'-ulps (2^-12): ~0.81 + pack noise
#define TAU2 0.02f      // hi/lo-split margin -> tier-3 (fp64 rescue)
#define LISTA_CAP 65536
#define LISTB_CAP 16384
#define TILE 1024       // points per gather work-item
#define MAX_ITEMS 2048
#define G_GATHER 1024

typedef unsigned int uint;
typedef unsigned short ushort;
using short8 = __attribute__((ext_vector_type(8))) short;
using f32x4  = __attribute__((ext_vector_type(4))) float;
using us8    = __attribute__((ext_vector_type(8))) unsigned short;

__device__ __forceinline__ ushort f2bf(float x) {
    uint u = __float_as_uint(x);
    u += 0x7fff + ((u >> 16) & 1);          // RNE
    return (ushort)(u >> 16);
}
__device__ __forceinline__ float bf2f(ushort h) {
    return __uint_as_float(((uint)h) << 16);
}
__device__ __forceinline__ uint umn(uint a, uint b) { return a < b ? a : b; }
__device__ __forceinline__ uint umx(uint a, uint b) { return a > b ? a : b; }

__device__ __forceinline__ void gload_lds16(const void* gsrc, void* ldst) {
    __builtin_amdgcn_global_load_lds(
        (const __attribute__((address_space(1))) unsigned int*)gsrc,
        (__attribute__((address_space(3))) unsigned int*)ldst,
        16, 0, 0);
}

// ---------------- prep: convC (blocks 0..255) + c2/c2q/c2d (blocks 256..257) ----------------
__global__ void prep_kernel(const float* __restrict__ C, ushort* __restrict__ Cp,
                            float* __restrict__ c2, float* __restrict__ c2q,
                            double* __restrict__ c2d) {
    int bid = blockIdx.x;
    if (bid < 256) {
        int e = bid * 256 + threadIdx.x;   // 0..65535
        int p = e >> 7, d = e & 127;
        float x = C[e];
        ushort h = f2bf(x);
        float lo = x - bf2f(h);
        Cp[(size_t)p * 256 + d] = h;
        Cp[(size_t)p * 256 + 128 + d] = f2bf(lo);
    } else {
        int k = (bid - 256) * 256 + threadIdx.x;
        if (k < K_CL) {
            const float* row = C + (size_t)k * DIM;
            float s = 0.f;
            double sd = 0.0;
            for (int d = 0; d < DIM; ++d) {
                s = fmaf(row[d], row[d], s);
                double v = (double)row[d];
                sd += v * v;
            }
            c2[k] = s;
            c2q[k] = s + 3072.0f;   // d' = c2q - 2*dot in [2048,4096)
            c2d[k] = sd;
        }
    }
}

// ---------------- TIER 1: hi-only MFMA GEMM + packed-u32 argmin ----------------
__global__ __launch_bounds__(256, 2)
void assign_hi(const float* __restrict__ F, const ushort* __restrict__ Cp,
               const float* __restrict__ c2qg, float* __restrict__ assign_out,
               int* __restrict__ cntA, int* __restrict__ listA,
               int* __restrict__ cntB, int* __restrict__ listB, int N) {
    __shared__ __align__(16) ushort Fs[BM * 128];    // 32768 B
    __shared__ __align__(16) ushort Cs[128 * 128];   // 32768 B

    const int tid  = threadIdx.x;
    const int lane = tid & 63;
    const int wave = tid >> 6;
    const int quad = lane >> 4;
    const int l15  = lane & 15;
    const int wy   = wave >> 1;     // point half
    const int wx   = wave & 1;      // center half
    const int p0   = blockIdx.x * BM;

#pragma unroll
    for (int t = 0; t < 8; ++t) {
        int G = tid + 256 * t;          // 0..2047 granules
        int r = G >> 4, pos = G & 15;
        int g = (pos & 8) | ((pos ^ r) & 7);
        int gp = p0 + r; if (gp >= N) gp = N - 1;
        const float* src = F + (size_t)gp * DIM + g * 8;
        float4 x0 = ((const float4*)src)[0];
        float4 x1 = ((const float4*)src)[1];
        us8 o;
        o[0] = f2bf(x0.x); o[1] = f2bf(x0.y); o[2] = f2bf(x0.z); o[3] = f2bf(x0.w);
        o[4] = f2bf(x1.x); o[5] = f2bf(x1.y); o[6] = f2bf(x1.z); o[7] = f2bf(x1.w);
        *((us8*)&Fs[(size_t)G * 8]) = o;
    }

    int prA[4], xA[4], cnB[4], xB[4];
#pragma unroll
    for (int i = 0; i < 4; ++i) {
        int pr = wy * 64 + i * 16 + l15;
        prA[i] = pr * 128; xA[i] = quad ^ (pr & 7);
    }
#pragma unroll
    for (int j = 0; j < 4; ++j) {
        int cn = wx * 64 + j * 16 + l15;
        cnB[j] = cn * 128; xB[j] = quad ^ (cn & 7);
    }
    int csrc[8];
#pragma unroll
    for (int t = 0; t < 8; ++t) {
        int G = t * 256 + wave * 64 + lane;
        int r = G >> 4, pos = G & 15;
        int g = (pos & 8) | ((pos ^ r) & 7);
        csrc[t] = r * 256 + g * 8;
    }
    float c2q[4][4];
    uint  kb [4][4];
#pragma unroll
    for (int cc = 0; cc < 4; ++cc)
#pragma unroll
        for (int j = 0; j < 4; ++j) {
            int k = cc * CC + wx * 64 + j * 16 + l15;
            c2q[cc][j] = c2qg[k];
            kb [cc][j] = (uint)k;
        }

    uint m1[16], m2[16];
#pragma unroll
    for (int i = 0; i < 16; ++i) { m1[i] = 0xFFFFFFFFu; m2[i] = 0xFFFFFFFFu; }

#pragma unroll 1
    for (int cc = 0; cc < 4; ++cc) {
        f32x4 acc[4][4];
#pragma unroll
        for (int i = 0; i < 4; ++i)
#pragma unroll
            for (int j = 0; j < 4; ++j) acc[i][j] = f32x4{0.f, 0.f, 0.f, 0.f};

        __syncthreads();
#pragma unroll
        for (int t = 0; t < 8; ++t)
            gload_lds16(Cp + (size_t)cc * CC * 256 + csrc[t],
                        &Cs[(size_t)(t * 256 + wave * 64) * 8]);
        __syncthreads();

#pragma unroll
        for (int s = 0; s < 4; ++s) {
            const int hs = (s & 2) << 2;
            const int ls = (s & 1) << 2;
            short8 a[4], b[4];
#pragma unroll
            for (int j = 0; j < 4; ++j)
                b[j] = *((const short8*)&Cs[cnB[j] + (hs | (xB[j] ^ ls)) * 8]);
#pragma unroll
            for (int i = 0; i < 4; ++i)
                a[i] = *((const short8*)&Fs[prA[i] + (hs | (xA[i] ^ ls)) * 8]);
#pragma unroll
            for (int i = 0; i < 4; ++i)
#pragma unroll
                for (int j = 0; j < 4; ++j)
                    acc[i][j] = __builtin_amdgcn_mfma_f32_16x16x32_bf16(
                        a[i], b[j], acc[i][j], 0, 0, 0);
        }

#pragma unroll
        for (int i = 0; i < 4; ++i)
#pragma unroll
            for (int reg = 0; reg < 4; ++reg) {
                int lr = i * 4 + reg;
#pragma unroll
                for (int j = 0; j < 4; ++j) {
                    float dq = fmaf(acc[i][j][reg], -2.0f, c2q[cc][j]);
                    uint x = (__float_as_uint(dq) & 0xFFFFFE00u) | kb[cc][j];
                    uint t = umx(x, m1[lr]);
                    m2[lr] = umn(m2[lr], t);
                    m1[lr] = umn(m1[lr], x);
                }
            }
    }

#pragma unroll
    for (int lr = 0; lr < 16; ++lr) {
        uint a1 = m1[lr], a2 = m2[lr];
#pragma unroll
        for (int m = 1; m <= 8; m <<= 1) {
            uint o1 = (uint)__shfl_xor((int)a1, m);
            uint o2 = (uint)__shfl_xor((int)a2, m);
            uint hi = umx(a1, o1);
            a1 = umn(a1, o1);
            a2 = umn(umn(a2, o2), hi);
        }
        m1[lr] = a1; m2[lr] = a2;
    }

    __syncthreads();
    uint* sm1 = (uint*)Cs;      // [2][128]
    uint* sm2 = sm1 + 256;

    if (l15 == 0) {
#pragma unroll
        for (int lr = 0; lr < 16; ++lr) {
            int pl = wy * 64 + (lr >> 2) * 16 + quad * 4 + (lr & 3);
            sm1[wx * 128 + pl] = m1[lr];
            sm2[wx * 128 + pl] = m2[lr];
        }
    }
    __syncthreads();

    if (tid < BM) {
        int p = p0 + tid;
        if (p < N) {
            uint a1 = sm1[tid], a2 = sm2[tid];
            uint b1 = sm1[128 + tid], b2 = sm2[128 + tid];
            uint hi = umx(a1, b1);
            uint M1 = umn(a1, b1);
            uint M2 = umn(umn(a2, b2), hi);
            assign_out[p] = (float)(M1 & 511u);
            if ((M2 & 0xFFFFFE00u) - (M1 & 0xFFFFFE00u) < GAPU) {
                int idx = atomicAdd(cntA, 1);
                if (idx < LISTA_CAP) listA[idx] = p;
                else {
                    int ib = atomicAdd(cntB, 1);
                    if (ib < LISTB_CAP) listB[ib] = p;
                }
            }
        }
    }
}

// ---------------- TIER 2: hi/lo-split MFMA re-rank of listA points ----------------
__global__ __launch_bounds__(256, 2)
void assign_lohi(const float* __restrict__ F, const ushort* __restrict__ Cp,
                 const float* __restrict__ c2g, float* __restrict__ assign_out,
                 const int* __restrict__ cntA, const int* __restrict__ listA,
                 int* __restrict__ cntB, int* __restrict__ listB, int N) {
    int cnt = *cntA; if (cnt > LISTA_CAP) cnt = LISTA_CAP;
    const int p0 = blockIdx.x * BM;
    if (p0 >= cnt) return;

    __shared__ __align__(16) ushort Fs[BM * 256];   // 65536 B
    __shared__ __align__(16) ushort Cs[CC * 64];    // 16384 B

    const int tid  = threadIdx.x;
    const int lane = tid & 63;
    const int wave = tid >> 6;
    const int quad = lane >> 4;
    const int l15  = lane & 15;
    const int wy   = wave >> 1;
    const int wx   = wave & 1;

    for (int G = tid; G < BM * 32; G += 256) {
        int r = G >> 5, pos = G & 31;
        int g = (pos & 24) | ((pos ^ r) & 7);
        int idx = p0 + r; if (idx >= cnt) idx = cnt - 1;
        int gp = listA[idx];
        const float* src = F + (size_t)gp * DIM + (g & 15) * 8;
        float4 x0 = ((const float4*)src)[0];
        float4 x1 = ((const float4*)src)[1];
        float xs[8] = {x0.x, x0.y, x0.z, x0.w, x1.x, x1.y, x1.z, x1.w};
        us8 o;
        if (g < 16) {
#pragma unroll
            for (int t = 0; t < 8; ++t) o[t] = f2bf(xs[t]);
        } else {
#pragma unroll
            for (int t = 0; t < 8; ++t) {
                ushort h = f2bf(xs[t]);
                o[t] = f2bf(xs[t] - bf2f(h));
            }
        }
        *((us8*)&Fs[(size_t)G * 8]) = o;
    }

    int aoff[4][2], boff[4][2];
#pragma unroll
    for (int i = 0; i < 4; ++i) {
        int pr = wy * 64 + i * 16 + l15;
#pragma unroll
        for (int s = 0; s < 2; ++s)
            aoff[i][s] = pr * 256 + (((s * 4 + quad) ^ (pr & 7)) * 8);
    }
#pragma unroll
    for (int j = 0; j < 4; ++j) {
        int cn = wx * 64 + j * 16 + l15;
#pragma unroll
        for (int s = 0; s < 2; ++s)
            boff[j][s] = cn * 64 + (((s * 4 + quad) ^ (cn & 7)) * 8);
    }
    int cpoff[4];
    ushort* ldsdst[4];
#pragma unroll
    for (int t = 0; t < 4; ++t) {
        int Gbase = t * 256 + wave * 64;
        int G = Gbase + lane;
        int r = G >> 3, pos = G & 7;
        int g = pos ^ (r & 7);
        cpoff[t] = r * 256 + g * 8;
        ldsdst[t] = &Cs[(size_t)Gbase * 8];
    }

    float best1[16], best2[16];
    int bidx[16];
#pragma unroll
    for (int i = 0; i < 16; ++i) { best1[i] = 3.4e38f; best2[i] = 3.4e38f; bidx[i] = 0; }

    for (int cc = 0; cc < K_CL / CC; ++cc) {
        const int ccbase = cc * (CC * 256);
        f32x4 acc[4][4];
#pragma unroll
        for (int i = 0; i < 4; ++i)
#pragma unroll
            for (int j = 0; j < 4; ++j) acc[i][j] = f32x4{0.f, 0.f, 0.f, 0.f};

#pragma unroll
        for (int st = 0; st < 4; ++st) {
            const int ak0 = st & 1;
            const int ak1 = (st < 2) ? (st + 2) : -1;

            __syncthreads();
#pragma unroll
            for (int t = 0; t < 4; ++t)
                gload_lds16(Cp + ccbase + st * 64 + cpoff[t], ldsdst[t]);
            __syncthreads();

#pragma unroll
            for (int s = 0; s < 2; ++s) {
                short8 b[4], a[4];
#pragma unroll
                for (int j = 0; j < 4; ++j)
                    b[j] = *((const short8*)&Cs[boff[j][s]]);
#pragma unroll
                for (int i = 0; i < 4; ++i)
                    a[i] = *((const short8*)&Fs[aoff[i][s] + ak0 * 64]);
#pragma unroll
                for (int i = 0; i < 4; ++i)
#pragma unroll
                    for (int j = 0; j < 4; ++j)
                        acc[i][j] = __builtin_amdgcn_mfma_f32_16x16x32_bf16(
                            a[i], b[j], acc[i][j], 0, 0, 0);
                if (ak1 >= 0) {
#pragma unroll
                    for (int i = 0; i < 4; ++i)
                        a[i] = *((const short8*)&Fs[aoff[i][s] + ak1 * 64]);
#pragma unroll
                    for (int i = 0; i < 4; ++i)
#pragma unroll
                        for (int j = 0; j < 4; ++j)
                            acc[i][j] = __builtin_amdgcn_mfma_f32_16x16x32_bf16(
                                a[i], b[j], acc[i][j], 0, 0, 0);
                }
            }
        }

        float c2v[4];
#pragma unroll
        for (int j = 0; j < 4; ++j)
            c2v[j] = c2g[cc * CC + wx * 64 + j * 16 + l15];
#pragma unroll
        for (int i = 0; i < 4; ++i)
#pragma unroll
            for (int reg = 0; reg < 4; ++reg) {
                int lr = i * 4 + reg;
#pragma unroll
                for (int j = 0; j < 4; ++j) {
                    float d = c2v[j] - 2.0f * acc[i][j][reg];
                    int k = cc * CC + wx * 64 + j * 16 + l15;
                    if (d < best1[lr]) { best2[lr] = best1[lr]; best1[lr] = d; bidx[lr] = k; }
                    else if (d < best2[lr]) best2[lr] = d;
                }
            }
    }

    __syncthreads();
    float* sb1 = (float*)Cs;
    float* sb2 = sb1 + 256;
    int*   sk  = (int*)(sb2 + 256);

#pragma unroll
    for (int lr = 0; lr < 16; ++lr) {
        float b1 = best1[lr], b2 = best2[lr];
        int k1 = bidx[lr];
#pragma unroll
        for (int m = 1; m <= 8; m <<= 1) {
            float ob1 = __shfl_xor(b1, m);
            float ob2 = __shfl_xor(b2, m);
            int   ok1 = __shfl_xor(k1, m);
            float nb2 = fminf(fmaxf(b1, ob1), fminf(b2, ob2));
            if (ob1 < b1 || (ob1 == b1 && ok1 < k1)) { b1 = ob1; k1 = ok1; }
            b2 = nb2;
        }
        best1[lr] = b1; best2[lr] = b2; bidx[lr] = k1;
    }
    if (l15 == 0) {
#pragma unroll
        for (int lr = 0; lr < 16; ++lr) {
            int pl = wy * 64 + (lr >> 2) * 16 + quad * 4 + (lr & 3);
            sb1[wx * 128 + pl] = best1[lr];
            sb2[wx * 128 + pl] = best2[lr];
            sk [wx * 128 + pl] = bidx[lr];
        }
    }
    __syncthreads();

    if (tid < BM && p0 + tid < cnt) {
        int p = listA[p0 + tid];
        float a1 = sb1[tid],       a2 = sb2[tid];        int akk = sk[tid];
        float c1 = sb1[128 + tid], cs2 = sb2[128 + tid]; int ckk = sk[128 + tid];
        float m2v = fminf(fmaxf(a1, c1), fminf(a2, cs2));
        float m1v; int mk;
        if (c1 < a1 || (c1 == a1 && ckk < akk)) { m1v = c1; mk = ckk; }
        else                                    { m1v = a1; mk = akk; }
        assign_out[p] = (float)mk;
        if (m2v - m1v < TAU2) {
            int ib = atomicAdd(cntB, 1);
            if (ib < LISTB_CAP) listB[ib] = p;
        }
    }
}

// ---------------- TIER 3: fp64 re-argmin for near-tie points ----------------
__global__ void rescue_kernel(const float* __restrict__ F, const float* __restrict__ C,
                              const double* __restrict__ c2d,
                              const int* __restrict__ cntB,
                              const int* __restrict__ listB,
                              float* __restrict__ assign_out) {
    __shared__ double Frow[DIM];
    __shared__ double bd[256];
    __shared__ int    bk[256];
    int cnt = *cntB;
    if (cnt > LISTB_CAP) cnt = LISTB_CAP;
    for (int r = blockIdx.x; r < cnt; r += gridDim.x) {
        int p = listB[r];
        if (threadIdx.x < DIM) Frow[threadIdx.x] = (double)F[(size_t)p * DIM + threadIdx.x];
        __syncthreads();
        double b1 = 1e300; int k1 = 0x7fffffff;
        for (int k = threadIdx.x; k < K_CL; k += 256) {
            const float* c = C + (size_t)k * DIM;
            double acc = 0.0;
            for (int d = 0; d < DIM; ++d) acc += Frow[d] * (double)c[d];
            double dd = c2d[k] - 2.0 * acc;
            if (dd < b1 || (dd == b1 && k < k1)) { b1 = dd; k1 = k; }
        }
        bd[threadIdx.x] = b1; bk[threadIdx.x] = k1;
        __syncthreads();
        for (int s = 128; s > 0; s >>= 1) {
            if (threadIdx.x < s) {
                double ob = bd[threadIdx.x + s]; int ok = bk[threadIdx.x + s];
                if (ob < bd[threadIdx.x] || (ob == bd[threadIdx.x] && ok < bk[threadIdx.x])) {
                    bd[threadIdx.x] = ob; bk[threadIdx.x] = ok;
                }
            }
            __syncthreads();
        }
        if (threadIdx.x == 0) assign_out[p] = (float)bk[0];
        __syncthreads();
    }
}

// ---------------- S1: block-aggregated per-cluster counts ----------------
__global__ void count_kernel(const float* __restrict__ assign_f,
                             int* __restrict__ gcount, int N) {
    __shared__ int h[K_CL];
    const int tid = threadIdx.x;
    h[tid] = 0; h[tid + 256] = 0;
    __syncthreads();
    int base = blockIdx.x * 1024;
#pragma unroll
    for (int t = 0; t < 4; ++t) {
        int p = base + tid + t * 256;
        if (p < N) atomicAdd(&h[(int)assign_f[p]], 1);
    }
    __syncthreads();
#pragma unroll
    for (int t = 0; t < 2; ++t) {
        int k = tid + t * 256;
        if (h[k]) atomicAdd(&gcount[k], h[k]);
    }
}

// ---------------- S2: scan + cursor init + work-item generation (1 block) ----------------
__global__ void scan_item_kernel(const int* __restrict__ gcount,
                                 int* __restrict__ offsets, int* __restrict__ cursor,
                                 int* __restrict__ items, int* __restrict__ itemCnt,
                                 int N) {
    __shared__ int s[K_CL];
    __shared__ int ic;
    int t = threadIdx.x;
    int v = gcount[t];
    s[t] = v;
    if (t == 0) ic = 0;
    __syncthreads();
    for (int off = 1; off < K_CL; off <<= 1) {
        int x = (t >= off) ? s[t - off] : 0;
        __syncthreads();
        s[t] += x;
        __syncthreads();
    }
    offsets[t] = s[t] - v;
    cursor[t]  = s[t] - v;
    if (t == K_CL - 1) offsets[K_CL] = N;
    int nIt = (v + TILE - 1) / TILE;
    int base = 0;
    if (nIt > 0) base = atomicAdd(&ic, nIt);
    for (int i = 0; i < nIt; ++i)
        if (base + i < MAX_ITEMS) items[base + i] = (t << 8) | i;
    __syncthreads();
    if (t == 0) *itemCnt = ic < MAX_ITEMS ? ic : MAX_ITEMS;
}

// ---------------- S3: block-aggregated scatter into cluster-contiguous order ----------------
__global__ void scatter_kernel(const float* __restrict__ assign_f,
                               int* __restrict__ cursor, int* __restrict__ idx, int N) {
    __shared__ int h[K_CL];
    __shared__ int b[K_CL];
    const int tid = threadIdx.x;
    h[tid] = 0; h[tid + 256] = 0;
    __syncthreads();
    int base = blockIdx.x * 1024;
    int a[4], r[4];
#pragma unroll
    for (int t = 0; t < 4; ++t) {
        int p = base + tid + t * 256;
        if (p < N) {
            a[t] = (int)assign_f[p];
            r[t] = atomicAdd(&h[a[t]], 1);
        } else a[t] = -1;
    }
    __syncthreads();
#pragma unroll
    for (int t = 0; t < 2; ++t) {
        int k = tid + t * 256;
        if (h[k]) b[k] = atomicAdd(&cursor[k], h[k]);
    }
    __syncthreads();
#pragma unroll
    for (int t = 0; t < 4; ++t) {
        if (a[t] >= 0) {
            int p = base + tid + t * 256;
            idx[b[a[t]] + r[t]] = p;
        }
    }
}

// ---------------- S4: balanced gather-sum, one block per work item ----------------
__global__ __launch_bounds__(256)
void gather_kernel(const float* __restrict__ F, const int* __restrict__ idx,
                   const int* __restrict__ offsets, const int* __restrict__ items,
                   const int* __restrict__ itemCnt, float* __restrict__ sums) {
    __shared__ int lidx[TILE];
    const int bid = blockIdx.x;
    if (bid >= *itemCnt) return;
    const int it    = items[bid];
    const int k     = it >> 8;
    const int chunk = it & 255;
    const int s   = offsets[k] + chunk * TILE;
    int e = offsets[k + 1];
    if (e > s + TILE) e = s + TILE;
    const int len = e - s;

    const int tid = threadIdx.x;
    for (int i = tid; i < len; i += 256) lidx[i] = idx[s + i];
    __syncthreads();

    const int d  = tid & 127;
    const int rg = tid >> 7;       // 0..1
    float acc = 0.f;
    for (int m0 = rg * 8; m0 < len; m0 += 16) {
        float v[8]; int ok[8];
#pragma unroll
        for (int t = 0; t < 8; ++t) {
            int m = m0 + t;
            ok[t] = (m < len);
            int p = lidx[ok[t] ? m : 0];
            v[t] = F[(size_t)p * DIM + d];
        }
#pragma unroll
        for (int t = 0; t < 8; ++t)
            if (ok[t]) acc += v[t];
    }
    unsafeAtomicAdd(&sums[(size_t)k * DIM + d], acc);
}

// ---------------- S5: new_centers = sums / max(counts,1) ----------------
__global__ void finalize_kernel(const float* __restrict__ sums,
                                const int* __restrict__ gcount,
                                float* __restrict__ out) {
    int i = blockIdx.x * 256 + threadIdx.x;   // 0..65535
    int k = i >> 7;
    out[i] = sums[i] / fmaxf((float)gcount[k], 1.0f);
}

extern "C" void kernel_launch(void* const* d_in, const int* in_sizes, int n_in,
                              void* d_out, int out_size, void* d_ws, size_t ws_size,
                              hipStream_t stream) {
    const float* F = (const float*)d_in[0];
    const float* C = (const float*)d_in[1];
    int N = in_sizes[0] / DIM;               // 200000

    float* out = (float*)d_out;
    float* centers_out = out;                // [512*128]
    float* assign_out  = out + K_CL * DIM;   // [N], as float

    // workspace layout (~1.7 MB)
    float*  sums    = (float*)d_ws;                   // 65536 f
    int*    gcount  = (int*)(sums + K_CL * DIM);      // 512
    int*    cursor  = gcount + K_CL;                  // 512
    int*    offsets = cursor + K_CL;                  // 516 (513 used)
    int*    itemCnt = offsets + 516;                  // 4
    int*    cntA    = itemCnt + 4;                    // 8: [0]=A, [1]=B
    int*    cntB    = cntA + 1;
    int*    items   = cntA + 8;                       // 2048
    int*    listA   = items + MAX_ITEMS;              // 65536
    int*    listB   = listA + LISTA_CAP;              // 16384
    float*  c2      = (float*)(listB + LISTB_CAP);    // 512
    float*  c2q     = c2 + K_CL;                      // 512
    double* c2d     = (double*)(c2q + K_CL);          // 512 (8B-aligned)
    ushort* Cp      = (ushort*)(c2d + K_CL);          // 512*256
    int*    idx     = (int*)(Cp + K_CL * 256);        // 200000

    // zero sums + gcount + cursor + offsets + itemCnt + cntA/cntB
    hipMemsetAsync(d_ws, 0,
                   (size_t)(K_CL * DIM) * sizeof(float) +
                   (512 + 512 + 516 + 4 + 8) * sizeof(int), stream);

    prep_kernel<<<258, 256, 0, stream>>>(C, Cp, c2, c2q, c2d);

    int nb = (N + BM - 1) / BM;              // 1563
    assign_hi<<<nb, 256, 0, stream>>>(F, Cp, c2q, assign_out, cntA, listA, cntB, listB, N);

    assign_lohi<<<LISTA_CAP / BM, 256, 0, stream>>>(F, Cp, c2, assign_out,
                                                    cntA, listA, cntB, listB, N);

    rescue_kernel<<<256, 256, 0, stream>>>(F, C, c2d, cntB, listB, assign_out);

    int cb = (N + 1023) / 1024;              // 196
    count_kernel    <<<cb, 256, 0, stream>>>(assign_out, gcount, N);
    scan_item_kernel<<<1, K_CL, 0, stream>>>(gcount, offsets, cursor, items, itemCnt, N);
    scatter_kernel  <<<cb, 256, 0, stream>>>(assign_out, cursor, idx, N);
    gather_kernel   <<<G_GATHER, 256, 0, stream>>>(F, idx, offsets, items, itemCnt, sums);
    finalize_kernel <<<K_CL * DIM / 256, 256, 0, stream>>>(sums, gcount, centers_out);
}